// Round 5
// baseline (1215.623 us; speedup 1.0000x reference)
//
#include <hip/hip_runtime.h>
#include <cstdint>
#include <cstddef>

typedef __bf16 bf16_t;
typedef __bf16 bf16x8 __attribute__((ext_vector_type(8)));
typedef float f32x4 __attribute__((ext_vector_type(4)));

#define B_  4
#define N_  64
#define FP_ 256
#define TP_ 32
#define V_  32000
#define D_  1024
#define L_  2048
#define M_  8192   // B_*L_
#define VT_ 125    // V_/256

// -------- async global->LDS (16B per lane, wave-uniform LDS base) --------
__device__ __forceinline__ void async_copy16(const void* g, void* l) {
  __builtin_amdgcn_global_load_lds(
      (__attribute__((address_space(1))) void*)g,
      (__attribute__((address_space(3))) void*)l,
      16, 0, 0);
}

// -------- x_prime (B,N,FP,TP) fp32 -> Xb (M,FP) bf16, m = b*L + t*N + n --------
__global__ __launch_bounds__(256) void k_convert_x(const float* __restrict__ xp,
                                                   bf16_t* __restrict__ Xb) {
  __shared__ float tile[256][33];
  const int tid = threadIdx.x;
  const int b = blockIdx.x >> 6;
  const int n = blockIdx.x & 63;
  const float* src = xp + (size_t)(b * N_ + n) * FP_ * TP_;   // (f,t) 256x32
#pragma unroll
  for (int i = 0; i < 32; i++) {
    int idx = i * 256 + tid;
    tile[idx >> 5][idx & 31] = src[idx];
  }
  __syncthreads();
#pragma unroll
  for (int t = 0; t < 32; t++) {
    Xb[(size_t)(b * L_ + t * N_ + n) * FP_ + tid] = (bf16_t)tile[tid][t];
  }
}

// -------- transpose+convert: src (R,C) fp32 -> dst (C,R) bf16 --------
__global__ void k_transpose_cvt(const float* __restrict__ src, bf16_t* __restrict__ dst,
                                int R, int C) {
  __shared__ float tile[64][65];
  int ct = blockIdx.x;
  int rt = blockIdx.y;
  int tid = threadIdx.x;
#pragma unroll
  for (int i = 0; i < 16; i++) {
    int idx = tid + i * 256;
    int a = idx >> 6, bc = idx & 63;
    tile[a][bc] = src[(size_t)(rt * 64 + a) * C + ct * 64 + bc];
  }
  __syncthreads();
#pragma unroll
  for (int i = 0; i < 16; i++) {
    int idx = tid + i * 256;
    int a = idx >> 6, bc = idx & 63;
    dst[(size_t)(ct * 64 + a) * R + rt * 64 + bc] = (bf16_t)tile[bc][a];
  }
}

#define BAR() asm volatile("s_barrier" ::: "memory")
#define VMW(n) asm volatile("s_waitcnt vmcnt(" #n ")" ::: "memory")
#define LGW(n) asm volatile("s_waitcnt lgkmcnt(" #n ")" ::: "memory")

// ======== GEMM1: P[pr][v] = exp(X[m]·Wt[v] + bias[v]) ======== (unchanged, proven)
__global__ __launch_bounds__(512, 2) void k_gemm1(
    const bf16_t* __restrict__ Xb, const bf16_t* __restrict__ Wt,
    const float* __restrict__ bias, bf16_t* __restrict__ P,
    float* __restrict__ rs_part, int mbase) {
  __shared__ __align__(16) bf16_t smem[65536];   // 128 KB: A 64K | B 64K ; epilogue 256x256

  const int tid = threadIdx.x;
  const int lane = tid & 63;
  const int wid = tid >> 6;          // 0..7
  const int wm = wid >> 2;           // 0..1
  const int wn = wid & 3;            // 0..3
  const int c16 = lane & 15, quad = lane >> 4;

  // bijective XCD-chunk swizzle (handles nwg % 8 != 0)
  const int nwg = (int)gridDim.x;
  const int q = nwg >> 3, r = nwg & 7;
  const int xcd = blockIdx.x & 7, bidx = (int)blockIdx.x >> 3;
  const int vb = (xcd < r) ? xcd * (q + 1) + bidx : r + xcd * q + bidx;
  const int vtile = vb % VT_;
  const int mtile = vb / VT_;

  const int v0 = vtile * 256;
  const int prow0 = mtile * 256;
  const int m0 = mbase + prow0;

  const int l3 = lane >> 3;
  const int cA = (lane & 7) ^ l3;
  const int grA = (l3 << 1) + (cA >> 2);
  const int gcA = (cA & 3) << 3;
  const int rA0 = (wid & 4) * 32 + (wid & 3) * 16;
  const int rB0 = (wid >> 1) * 64 + (wid & 1) * 16;

  const bf16_t* gA = Xb + (size_t)(m0 + grA) * FP_ + gcA;
  const bf16_t* gB = Wt + (size_t)(v0 + grA) * FP_ + gcA;

  float bv[4];
#pragma unroll
  for (int J = 0; J < 4; J++)
    bv[J] = bias[v0 + wn * 64 + (J >> 1) * 32 + (J & 1) * 16 + c16];

  f32x4 acc[8][4];
#pragma unroll
  for (int i = 0; i < 8; i++)
#pragma unroll
    for (int j = 0; j < 4; j++) acc[i][j] = (f32x4){0.f, 0.f, 0.f, 0.f};

  bf16x8 af[4][2], bfr[2][2];

#define G1_STAGE_A(buf, t, half)                                        \
  do {                                                                  \
    int r0_ = rA0 + (half) * 64;                                        \
    const bf16_t* s_ = gA + (size_t)r0_ * FP_ + (t) * 64;               \
    async_copy16(s_,      &smem[((buf) * 2 + 0) * 8192 + r0_ * 32]);    \
    async_copy16(s_ + 32, &smem[((buf) * 2 + 1) * 8192 + r0_ * 32]);    \
  } while (0)
#define G1_STAGE_B(buf, t, half)                                        \
  do {                                                                  \
    int r0_ = rB0 + (half) * 32;                                        \
    const bf16_t* s_ = gB + (size_t)r0_ * FP_ + (t) * 64;               \
    async_copy16(s_,      &smem[32768 + ((buf) * 2 + 0) * 8192 + r0_ * 32]); \
    async_copy16(s_ + 32, &smem[32768 + ((buf) * 2 + 1) * 8192 + r0_ * 32]); \
  } while (0)
#define G1_READ_A(buf, mh)                                              \
  do {                                                                  \
    _Pragma("unroll")                                                   \
    for (int i_ = 0; i_ < 4; i_++) {                                    \
      int r_ = wm * 128 + (mh) * 64 + i_ * 16 + c16;                    \
      int pa_ = r_ >> 1;                                                \
      int cz_ = ((((r_ & 1) << 2) | quad) ^ (pa_ & 7)) << 3;            \
      af[i_][0] = *(const bf16x8*)&smem[((buf) * 2 + 0) * 8192 + pa_ * 64 + cz_]; \
      af[i_][1] = *(const bf16x8*)&smem[((buf) * 2 + 1) * 8192 + pa_ * 64 + cz_]; \
    }                                                                   \
  } while (0)
#define G1_READ_B(buf, nh)                                              \
  do {                                                                  \
    _Pragma("unroll")                                                   \
    for (int j_ = 0; j_ < 2; j_++) {                                    \
      int r_ = wn * 64 + (nh) * 32 + j_ * 16 + c16;                     \
      int pn_ = r_ >> 1;                                                \
      int cz_ = ((((r_ & 1) << 2) | quad) ^ (pn_ & 7)) << 3;            \
      bfr[j_][0] = *(const bf16x8*)&smem[32768 + ((buf) * 2 + 0) * 8192 + pn_ * 64 + cz_]; \
      bfr[j_][1] = *(const bf16x8*)&smem[32768 + ((buf) * 2 + 1) * 8192 + pn_ * 64 + cz_]; \
    }                                                                   \
  } while (0)
#define G1_MFMA16(mh, nh)                                               \
  do {                                                                  \
    __builtin_amdgcn_s_setprio(1);                                      \
    _Pragma("unroll")                                                   \
    for (int i_ = 0; i_ < 4; i_++)                                      \
      _Pragma("unroll")                                                 \
      for (int j_ = 0; j_ < 2; j_++) {                                  \
        acc[(mh)*4 + i_][(nh)*2 + j_] = __builtin_amdgcn_mfma_f32_16x16x32_bf16( \
            af[i_][0], bfr[j_][0], acc[(mh)*4 + i_][(nh)*2 + j_], 0, 0, 0);      \
        acc[(mh)*4 + i_][(nh)*2 + j_] = __builtin_amdgcn_mfma_f32_16x16x32_bf16( \
            af[i_][1], bfr[j_][1], acc[(mh)*4 + i_][(nh)*2 + j_], 0, 0, 0);      \
      }                                                                 \
    __builtin_amdgcn_s_setprio(0);                                      \
  } while (0)

  G1_STAGE_A(0, 0, 0); G1_STAGE_B(0, 0, 0); G1_STAGE_B(0, 0, 1); G1_STAGE_A(0, 0, 1);
  VMW(0);
  BAR();

  const int NT = 4;   // FP_/64
#pragma unroll
  for (int t = 0; t < NT; ++t) {
    const int cur = t & 1, nb = cur ^ 1;
    const bool pf = (t + 1 < NT);

    G1_READ_A(cur, 0); G1_READ_B(cur, 0);
    if (pf) G1_STAGE_A(nb, t + 1, 0);
    LGW(8);
    BAR();
    LGW(0);
    G1_MFMA16(0, 0);
    if (pf) VMW(4); else VMW(2);
    BAR();

    G1_READ_B(cur, 1);
    if (pf) G1_STAGE_B(nb, t + 1, 0);
    BAR();
    LGW(0);
    G1_MFMA16(0, 1);
    if (pf) VMW(4); else VMW(0);
    BAR();

    G1_READ_A(cur, 1);
    if (pf) G1_STAGE_B(nb, t + 1, 1);
    BAR();
    LGW(0);
    G1_MFMA16(1, 1);
    BAR();

    G1_READ_B(cur, 0);
    if (pf) G1_STAGE_A(nb, t + 1, 1);
    BAR();
    LGW(0);
    G1_MFMA16(1, 0);
    if (pf) {
      VMW(4);
      BAR();
    }
  }

  // epilogue pass 1: exp + bf16 round + per-wave 64-col partial rowsum
#pragma unroll
  for (int I = 0; I < 8; I++) {
    int rowb = wm * 128 + (I >> 2) * 64 + (I & 3) * 16;
#pragma unroll
    for (int e = 0; e < 4; e++) {
      int row = rowb + quad * 4 + e;
      float s = 0.0f;
#pragma unroll
      for (int J = 0; J < 4; J++) {
        float p = __expf(acc[I][J][e] + bv[J]);
        float pf32 = (float)(bf16_t)p;
        acc[I][J][e] = pf32;
        s += pf32;
      }
#pragma unroll
      for (int off = 1; off < 16; off <<= 1) s += __shfl_xor(s, off, 16);
      if (c16 == 0)
        rs_part[(size_t)(prow0 + row) * 512 + vtile * 4 + wn] = s;
    }
  }

  // epilogue pass 2: stage bf16 tile in LDS, coalesced b128 stores
  __syncthreads();
#pragma unroll
  for (int I = 0; I < 8; I++) {
    int rowb = wm * 128 + (I >> 2) * 64 + (I & 3) * 16;
#pragma unroll
    for (int e = 0; e < 4; e++) {
      int row = rowb + quad * 4 + e;
#pragma unroll
      for (int J = 0; J < 4; J++) {
        int ch = wn * 8 + (J >> 1) * 4 + (J & 1) * 2 + (c16 >> 3);
        smem[row * 256 + ((ch ^ (row & 7)) << 3) + (c16 & 7)] = (bf16_t)acc[I][J][e];
      }
    }
  }
  __syncthreads();
#pragma unroll
  for (int it = 0; it < 16; it++) {
    int idx2 = it * 512 + tid;
    int row = idx2 >> 5, ch = idx2 & 31;
    *(bf16x8*)&P[(size_t)(prow0 + row) * V_ + v0 + ch * 8] =
        *(const bf16x8*)&smem[row * 256 + ((ch ^ (row & 7)) << 3)];
  }
#undef G1_STAGE_A
#undef G1_STAGE_B
#undef G1_READ_A
#undef G1_READ_B
#undef G1_MFMA16
}

// -------- rowsum reduce --------
__global__ void k_rowsum_reduce(const float* __restrict__ rs_part,
                                float* __restrict__ rowsum, int mbase) {
  int row = blockIdx.x * 4 + (threadIdx.x >> 6);
  int lane = threadIdx.x & 63;
  float s = 0.0f;
  for (int j = lane; j < VT_ * 4; j += 64) s += rs_part[(size_t)row * 512 + j];
#pragma unroll
  for (int off = 32; off >= 1; off >>= 1) s += __shfl_xor(s, off, 64);
  if (lane == 0) rowsum[mbase + row] = s;
}

// ======== GEMM2: 256x256, BK=64, 8 waves (2m x 4n), software-pipelined frags.
// Quadrants Q0=(m0,n0) Q1=(m0,n1) Q2=(m1,n1) Q3=(m1,n0). Per K-tile: 2 barriers,
// counted vmcnt(2)/vmcnt(0) gates; every ds_read cluster overlaps an MFMA cluster
// (frags for phase p read during phase p-1's MFMAs; compiler emits counted lgkm).
__global__ __launch_bounds__(512, 2) void k_gemm2(
    const bf16_t* __restrict__ P, const bf16_t* __restrict__ Et,
    float* __restrict__ partial, int mtiles, int chunkrows, int kper) {
  __shared__ __align__(16) bf16_t ldsA[2][2][8192];   // [buf][kk][pair-row form]
  __shared__ __align__(16) bf16_t ldsB[2][2][8192];

  const int tid = threadIdx.x;
  const int lane = tid & 63;
  const int wid = tid >> 6;
  const int wm = wid >> 2;
  const int wn = wid & 3;
  const int c16 = lane & 15, quad = lane >> 4;

  const int nwg = (int)gridDim.x;
  const int xcd = blockIdx.x & 7;
  const int vb = xcd * (nwg >> 3) + ((int)blockIdx.x >> 3);
  const int dtile = vb & 3;
  const int rest = vb >> 2;
  const int mtile = rest % mtiles;
  const int kslice = rest / mtiles;

  const int d0 = dtile * 256;
  const int prow0 = mtile * 256;
  const int kbase = kslice * kper;
  float* __restrict__ o = partial + (size_t)kslice * chunkrows * D_;

  const int l3 = lane >> 3;
  const int cA = (lane & 7) ^ l3;
  const int grA = (l3 << 1) + (cA >> 2);
  const int gcA = (cA & 3) << 3;

  const int rA0 = (wid & 4) * 32 + (wid & 3) * 16;   // A half0: rows 0-63,128-191
  const int rB0 = (wid >> 1) * 64 + (wid & 1) * 16;  // B half0: rows 0-31,64-95,128-159,192-223

  const bf16_t* gA = P  + (size_t)(prow0 + grA) * V_ + kbase + gcA;
  const bf16_t* gB = Et + (size_t)(d0   + grA) * V_ + kbase + gcA;

  f32x4 acc[8][4];
#pragma unroll
  for (int i = 0; i < 8; i++)
#pragma unroll
    for (int j = 0; j < 4; j++) acc[i][j] = (f32x4){0.f, 0.f, 0.f, 0.f};

  // fragment registers: afm0 = A rows [wm*128+0..63], afm1 = [.. 64..127]
  // bB0 = B cols [wn*64+0..31], bB1 = [.. 32..63] (bB1 re-used for Q3's B0 re-read)
  bf16x8 afm0[4][2], afm1[4][2], bB0[2][2], bB1[2][2];

#define STAGE_A(buf, t, half)                                          \
  do {                                                                 \
    int r0_ = rA0 + (half) * 64;                                       \
    const bf16_t* s_ = gA + (size_t)r0_ * V_ + (t) * 64;               \
    async_copy16(s_,      &ldsA[buf][0][r0_ * 32]);                    \
    async_copy16(s_ + 32, &ldsA[buf][1][r0_ * 32]);                    \
  } while (0)
#define STAGE_B(buf, t, half)                                          \
  do {                                                                 \
    int r0_ = rB0 + (half) * 32;                                       \
    const bf16_t* s_ = gB + (size_t)r0_ * V_ + (t) * 64;               \
    async_copy16(s_,      &ldsB[buf][0][r0_ * 32]);                    \
    async_copy16(s_ + 32, &ldsB[buf][1][r0_ * 32]);                    \
  } while (0)
#define LDSOFF(r_) (((r_) >> 1) * 64 + (((((r_) & 1) << 2) | quad) ^ (((r_) >> 1) & 7)) * 8)
#define READ_A_HALF(buf, base_i, dst)                                  \
  do { _Pragma("unroll")                                               \
    for (int i_ = 0; i_ < 4; i_++) {                                   \
      int r_ = wm * 128 + ((base_i) + i_) * 16 + c16;                  \
      int off_ = LDSOFF(r_);                                           \
      dst[i_][0] = *(const bf16x8*)&ldsA[buf][0][off_];                \
      dst[i_][1] = *(const bf16x8*)&ldsA[buf][1][off_];                \
    } } while (0)
#define READ_B_PAIR(buf, base_j, dst)                                  \
  do { _Pragma("unroll")                                               \
    for (int j_ = 0; j_ < 2; j_++) {                                   \
      int r_ = wn * 64 + ((base_j) + j_) * 16 + c16;                   \
      int off_ = LDSOFF(r_);                                           \
      dst[j_][0] = *(const bf16x8*)&ldsB[buf][0][off_];                \
      dst[j_][1] = *(const bf16x8*)&ldsB[buf][1][off_];                \
    } } while (0)
#define Q_MFMA(bi, bj, AF, BF)                                         \
  do {                                                                 \
    __builtin_amdgcn_s_setprio(1);                                     \
    _Pragma("unroll")                                                  \
    for (int kk_ = 0; kk_ < 2; kk_++)                                  \
      _Pragma("unroll")                                                \
      for (int i_ = 0; i_ < 4; i_++)                                   \
        _Pragma("unroll")                                              \
        for (int j_ = 0; j_ < 2; j_++)                                 \
          acc[(bi) + i_][(bj) + j_] =                                  \
            __builtin_amdgcn_mfma_f32_16x16x32_bf16(                   \
              AF[i_][kk_], BF[j_][kk_], acc[(bi) + i_][(bj) + j_], 0, 0, 0); \
    __builtin_amdgcn_s_setprio(0);                                     \
  } while (0)

  // prologue: stage tile 0 fully, drain, read Q0(t=0) frags
  STAGE_A(0, 0, 0); STAGE_A(0, 0, 1); STAGE_B(0, 0, 0); STAGE_B(0, 0, 1);
  VMW(0);
  BAR();
  READ_A_HALF(0, 0, afm0);
  READ_B_PAIR(0, 0, bB0);

  const int NT = kper >> 6;
  for (int t = 0; t < NT; ++t) {
    const int cur = t & 1, nb = cur ^ 1;
    const bool pf = (t + 1 < NT);

    // ---- p0: MFMA(Q0) ∥ read B1(t) ∥ stage A(t+1) ----
    if (pf) { STAGE_A(nb, t + 1, 0); STAGE_A(nb, t + 1, 1); }
    READ_B_PAIR(cur, 2, bB1);
    Q_MFMA(0, 0, afm0, bB0);

    // ---- p1: MFMA(Q1) ∥ read A1(t) ∥ stage B(t+1) ----
    if (pf) { STAGE_B(nb, t + 1, 0); STAGE_B(nb, t + 1, 1); }
    READ_A_HALF(cur, 4, afm1);
    Q_MFMA(0, 2, afm0, bB1);

    // ---- p2: MFMA(Q2) ∥ re-read B0(t) into bB1 regs (source order: MFMA first) ----
    Q_MFMA(4, 2, afm1, bB1);
    READ_B_PAIR(cur, 0, bB1);
    VMW(2);                 // A-h0/A-h1/B-h0 of t+1 landed; B-h1 may stay in flight
    BAR();

    // ---- p3: MFMA(Q3) ∥ read Q0(t+1) from other buffer ----
    if (pf) { READ_A_HALF(nb, 0, afm0); READ_B_PAIR(nb, 0, bB0); }
    Q_MFMA(4, 0, afm1, bB1);
    if (pf) {
      VMW(0);               // B-h1(t+1) (issued ~2 phases ago) landed
      BAR();
    }
  }

  // epilogue: acc[I][J] -> row = wm*128 + I*16 + quad*4 + e, col = wn*64 + J*16 + c16
#pragma unroll
  for (int I = 0; I < 8; I++) {
    int rowb = wm * 128 + I * 16;
#pragma unroll
    for (int e = 0; e < 4; e++) {
      int pr = prow0 + rowb + quad * 4 + e;
#pragma unroll
      for (int J = 0; J < 4; J++) {
        int d = d0 + wn * 64 + J * 16 + c16;
        o[(size_t)pr * D_ + d] = acc[I][J][e];
      }
    }
  }
#undef STAGE_A
#undef STAGE_B
#undef LDSOFF
#undef READ_A_HALF
#undef READ_B_PAIR
#undef Q_MFMA
}

#undef BAR
#undef VMW
#undef LGW

// -------- finalize: out[mbase+lr][:] = (sum_z partial[z]) / rowsum --------
__global__ void k_finalize(const float* __restrict__ partial,
                           const float* __restrict__ rowsum, float* __restrict__ out,
                           int mbase, int rows, int ks) {
  int i = blockIdx.x * 256 + threadIdx.x;   // over rows*D/4
  int lr = i >> 8;                          // /(D_/4)
  float inv = 1.0f / rowsum[mbase + lr];
  f32x4 s = (f32x4){0.f, 0.f, 0.f, 0.f};
  for (int z = 0; z < ks; z++) {
    f32x4 a = ((const f32x4*)(partial + (size_t)z * rows * D_))[i];
    s.x += a.x; s.y += a.y; s.z += a.z; s.w += a.w;
  }
  s.x *= inv; s.y *= inv; s.z *= inv; s.w *= inv;
  ((f32x4*)out)[(size_t)mbase * (D_ / 4) + i] = s;
}

// ======== host ========
extern "C" void kernel_launch(void* const* d_in, const int* in_sizes, int n_in,
                              void* d_out, int out_size, void* d_ws, size_t ws_size,
                              hipStream_t stream) {
  const float* xp   = (const float*)d_in[0];   // (B,N,FP,TP)
  const float* E    = (const float*)d_in[1];   // (V,D)
  const float* W    = (const float*)d_in[2];   // (FP,V)
  const float* bias = (const float*)d_in[3];   // (V)
  float* out = (float*)d_out;                  // (M,D)

  char* ws = (char*)d_ws;
  const size_t szXb = (size_t)M_ * FP_ * 2;
  const size_t szWt = (size_t)V_ * FP_ * 2;
  const size_t szEt = (size_t)D_ * V_ * 2;
  const size_t szRs = (size_t)M_ * 4;
  bf16_t* Xb = (bf16_t*)ws;
  bf16_t* Wt = (bf16_t*)(ws + szXb);
  bf16_t* Et = (bf16_t*)(ws + szXb + szWt);
  float* rowsum = (float*)(ws + szXb + szWt + szEt);
  const size_t fixed = szXb + szWt + szEt + szRs;

  const int copt[4] = {8192, 4096, 2048, 1024};
  const int kopt[4] = {2, 4, 10, 20};
  int chunk = 1024, ksv = 20;
  size_t avail = (ws_size > fixed) ? ws_size - fixed : 0;
  for (int i = 0; i < 4; i++) {
    size_t need = (size_t)copt[i] * V_ * 2 + (size_t)kopt[i] * copt[i] * D_ * 4
                + (size_t)copt[i] * 512 * 4;
    if (need <= avail) { chunk = copt[i]; ksv = kopt[i]; break; }
  }
  bf16_t* P = (bf16_t*)(ws + fixed);
  float* partial = (float*)(ws + fixed + (size_t)chunk * V_ * 2);
  float* rs_part = (float*)(ws + fixed + (size_t)chunk * V_ * 2
                            + (size_t)ksv * chunk * D_ * 4);
  const int kper = V_ / ksv;

  k_convert_x<<<B_ * N_, 256, 0, stream>>>(xp, Xb);
  {
    dim3 g(V_ / 64, FP_ / 64);
    k_transpose_cvt<<<g, 256, 0, stream>>>(W, Wt, FP_, V_);
  }
  {
    dim3 g(D_ / 64, V_ / 64);
    k_transpose_cvt<<<g, 256, 0, stream>>>(E, Et, V_, D_);
  }

  for (int mb = 0; mb < M_; mb += chunk) {
    int rows = M_ - mb;
    if (rows > chunk) rows = chunk;

    int nwg1 = VT_ * (rows / 256);
    k_gemm1<<<nwg1, 512, 0, stream>>>(Xb, Wt, bias, P, rs_part, mb);
    k_rowsum_reduce<<<rows / 4, 256, 0, stream>>>(rs_part, rowsum, mb);

    int mt = rows / 256;
    int nwg2 = 4 * mt * ksv;
    k_gemm2<<<nwg2, 512, 0, stream>>>(P, Et, partial, mt, rows, kper);

    k_finalize<<<rows, 256, 0, stream>>>(partial, rowsum, out, mb, rows, ksv);
  }
}

// Round 7
// 1148.377 us; speedup vs baseline: 1.0586x; 1.0586x over previous
//
#include <hip/hip_runtime.h>
#include <cstdint>
#include <cstddef>

typedef __bf16 bf16_t;
typedef __bf16 bf16x8 __attribute__((ext_vector_type(8)));
typedef float f32x4 __attribute__((ext_vector_type(4)));

#define B_  4
#define N_  64
#define FP_ 256
#define TP_ 32
#define V_  32000
#define D_  1024
#define L_  2048
#define M_  8192   // B_*L_
#define VT_ 125    // V_/256

// -------- async global->LDS (16B per lane, wave-uniform LDS base) --------
__device__ __forceinline__ void async_copy16(const void* g, void* l) {
  __builtin_amdgcn_global_load_lds(
      (__attribute__((address_space(1))) void*)g,
      (__attribute__((address_space(3))) void*)l,
      16, 0, 0);
}

// -------- x_prime (B,N,FP,TP) fp32 -> Xb (M,FP) bf16, m = b*L + t*N + n --------
__global__ __launch_bounds__(256) void k_convert_x(const float* __restrict__ xp,
                                                   bf16_t* __restrict__ Xb) {
  __shared__ float tile[256][33];
  const int tid = threadIdx.x;
  const int b = blockIdx.x >> 6;
  const int n = blockIdx.x & 63;
  const float* src = xp + (size_t)(b * N_ + n) * FP_ * TP_;   // (f,t) 256x32
#pragma unroll
  for (int i = 0; i < 32; i++) {
    int idx = i * 256 + tid;
    tile[idx >> 5][idx & 31] = src[idx];
  }
  __syncthreads();
#pragma unroll
  for (int t = 0; t < 32; t++) {
    Xb[(size_t)(b * L_ + t * N_ + n) * FP_ + tid] = (bf16_t)tile[tid][t];
  }
}

// -------- transpose+convert: src (R,C) fp32 -> dst (C,R) bf16 --------
__global__ void k_transpose_cvt(const float* __restrict__ src, bf16_t* __restrict__ dst,
                                int R, int C) {
  __shared__ float tile[64][65];
  int ct = blockIdx.x;
  int rt = blockIdx.y;
  int tid = threadIdx.x;
#pragma unroll
  for (int i = 0; i < 16; i++) {
    int idx = tid + i * 256;
    int a = idx >> 6, bc = idx & 63;
    tile[a][bc] = src[(size_t)(rt * 64 + a) * C + ct * 64 + bc];
  }
  __syncthreads();
#pragma unroll
  for (int i = 0; i < 16; i++) {
    int idx = tid + i * 256;
    int a = idx >> 6, bc = idx & 63;
    dst[(size_t)(ct * 64 + a) * R + rt * 64 + bc] = (bf16_t)tile[bc][a];
  }
}

#define BAR() asm volatile("s_barrier" ::: "memory")
#define VMW(n) asm volatile("s_waitcnt vmcnt(" #n ")" ::: "memory")

// ======== GEMM1: P[pr][v] = exp(X[m]·Wt[v] + bias[v]) ========
// Ring-3 / BK=32 / minimal-sync: per K-tile 1 barrier + 1 counted vmcnt(4);
// stage distance = 2 tiles. 8 waves (2m x 4n), wave tile 128x64, acc[8][4].
// rs_part: one slot per (row, vtile, wn) — no atomics, no races.
__global__ __launch_bounds__(512, 2) void k_gemm1(
    const bf16_t* __restrict__ Xb, const bf16_t* __restrict__ Wt,
    const float* __restrict__ bias, bf16_t* __restrict__ P,
    float* __restrict__ rs_part, int mbase) {
  // ring: buf b -> A at smem + b*16384, B at +8192 (3 bufs = 48K elems);
  // epilogue reuses all 64K elems (128 KB) for the 256x256 bf16 tile.
  __shared__ __align__(16) bf16_t smem[65536];

  const int tid = threadIdx.x;
  const int lane = tid & 63;
  const int wid = tid >> 6;          // 0..7
  const int wm = wid >> 2;           // 0..1
  const int wn = wid & 3;            // 0..3
  const int c16 = lane & 15, quad = lane >> 4;

  // bijective XCD-chunk swizzle (handles nwg % 8 != 0)
  const int nwg = (int)gridDim.x;
  const int q = nwg >> 3, r = nwg & 7;
  const int xcd = blockIdx.x & 7, bidx = (int)blockIdx.x >> 3;
  const int vb = (xcd < r) ? xcd * (q + 1) + bidx : r + xcd * q + bidx;
  const int vtile = vb % VT_;
  const int mtile = vb / VT_;

  const int v0 = vtile * 256;
  const int prow0 = mtile * 256;
  const int m0 = mbase + prow0;

  // staging lane geometry (verified stage/read involution pair)
  const int l3 = lane >> 3;
  const int cA = (lane & 7) ^ l3;
  const int grA = (l3 << 1) + (cA >> 2);   // row offset in 16-row window
  const int gcA = (cA & 3) << 3;           // elem offset in 32-wide K

  const bf16_t* srcA0 = Xb + (size_t)(m0 + (wid * 2 + 0) * 16 + grA) * FP_ + gcA;
  const bf16_t* srcA1 = Xb + (size_t)(m0 + (wid * 2 + 1) * 16 + grA) * FP_ + gcA;
  const bf16_t* srcB0 = Wt + (size_t)(v0 + (wid * 2 + 0) * 16 + grA) * FP_ + gcA;
  const bf16_t* srcB1 = Wt + (size_t)(v0 + (wid * 2 + 1) * 16 + grA) * FP_ + gcA;
  const int ldsOfs0 = (wid * 2 + 0) * 16 * 32;
  const int ldsOfs1 = (wid * 2 + 1) * 16 * 32;

  // bias (per-lane cols): issued before stages; prologue VMW(0) drains all.
  float bv[4];
#pragma unroll
  for (int J = 0; J < 4; J++)
    bv[J] = bias[v0 + wn * 64 + J * 16 + c16];

  f32x4 acc[8][4];
#pragma unroll
  for (int i = 0; i < 8; i++)
#pragma unroll
    for (int j = 0; j < 4; j++) acc[i][j] = (f32x4){0.f, 0.f, 0.f, 0.f};

#define G1_STAGE(buf, t)                                                 \
  do {                                                                   \
    async_copy16(srcA0 + (t) * 32, &smem[(buf) * 16384 + ldsOfs0]);      \
    async_copy16(srcA1 + (t) * 32, &smem[(buf) * 16384 + ldsOfs1]);      \
    async_copy16(srcB0 + (t) * 32, &smem[(buf) * 16384 + 8192 + ldsOfs0]); \
    async_copy16(srcB1 + (t) * 32, &smem[(buf) * 16384 + 8192 + ldsOfs1]); \
  } while (0)

  // prologue: stage tiles 0,1 into bufs 0,1; drain everything once.
  G1_STAGE(0, 0);
  G1_STAGE(1, 1);
  VMW(0);
  BAR();

  const int NT = FP_ >> 5;   // 8
  int cur = 0;
  for (int t = 0; t < NT; ++t) {
    if (t > 0) {
      if (t < NT - 1) VMW(4);   // drains stage issued 2 tiles ago = this tile's data
      else            VMW(0);   // stage stream stopped; full drain for last tile
      BAR();
    }
    const int nx2 = (cur == 0) ? 2 : cur - 1;
    if (t < NT - 2) G1_STAGE(nx2, t + 2);

    const int bo = cur * 16384;
    bf16x8 bfr[4];
#pragma unroll
    for (int j = 0; j < 4; j++) {
      int rn = wn * 64 + j * 16 + c16;
      int pn = rn >> 1;
      int cz = (((rn & 1) << 2) | quad) ^ (pn & 7);
      bfr[j] = *(const bf16x8*)&smem[bo + 8192 + pn * 64 + (cz << 3)];
    }
    __builtin_amdgcn_s_setprio(1);
#pragma unroll
    for (int i = 0; i < 8; i++) {
      int rr = wm * 128 + i * 16 + c16;
      int pa = rr >> 1;
      int cz = (((rr & 1) << 2) | quad) ^ (pa & 7);
      bf16x8 a = *(const bf16x8*)&smem[bo + pa * 64 + (cz << 3)];
#pragma unroll
      for (int j = 0; j < 4; j++)
        acc[i][j] = __builtin_amdgcn_mfma_f32_16x16x32_bf16(a, bfr[j], acc[i][j], 0, 0, 0);
    }
    __builtin_amdgcn_s_setprio(0);
    cur = (cur == 2) ? 0 : cur + 1;
  }

  // epilogue pass 1 (registers only): exp + bf16 round + per-wave 64-col rowsum
#pragma unroll
  for (int I = 0; I < 8; I++) {
    int rowb = wm * 128 + I * 16;
#pragma unroll
    for (int e = 0; e < 4; e++) {
      int row = rowb + quad * 4 + e;
      float s = 0.0f;
#pragma unroll
      for (int J = 0; J < 4; J++) {
        float p = __expf(acc[I][J][e] + bv[J]);
        float pf32 = (float)(bf16_t)p;
        acc[I][J][e] = pf32;
        s += pf32;
      }
#pragma unroll
      for (int off = 1; off < 16; off <<= 1) s += __shfl_xor(s, off, 16);
      if (c16 == 0)
        rs_part[(size_t)(prow0 + row) * 512 + vtile * 4 + wn] = s;
    }
  }

  // epilogue pass 2: stage bf16 tile in LDS (row&7 XOR chunk swizzle), then
  // coalesced b128 stores.
  __syncthreads();
#pragma unroll
  for (int I = 0; I < 8; I++) {
    int rowb = wm * 128 + I * 16;
#pragma unroll
    for (int e = 0; e < 4; e++) {
      int row = rowb + quad * 4 + e;
#pragma unroll
      for (int J = 0; J < 4; J++) {
        int ch = wn * 8 + J * 2 + (c16 >> 3);   // col/8 = (wn*64 + J*16 + c16)/8
        smem[row * 256 + ((ch ^ (row & 7)) << 3) + (c16 & 7)] = (bf16_t)acc[I][J][e];
      }
    }
  }
  __syncthreads();
#pragma unroll
  for (int it = 0; it < 16; it++) {
    int idx2 = it * 512 + tid;
    int row = idx2 >> 5, ch = idx2 & 31;
    *(bf16x8*)&P[(size_t)(prow0 + row) * V_ + v0 + ch * 8] =
        *(const bf16x8*)&smem[row * 256 + ((ch ^ (row & 7)) << 3)];
  }
#undef G1_STAGE
}

// -------- rowsum reduce: rowsum[mbase+row] = sum of 500 per-wave partials --------
__global__ void k_rowsum_reduce(const float* __restrict__ rs_part,
                                float* __restrict__ rowsum, int mbase) {
  int row = blockIdx.x * 4 + (threadIdx.x >> 6);
  int lane = threadIdx.x & 63;
  float s = 0.0f;
  for (int j = lane; j < VT_ * 4; j += 64) s += rs_part[(size_t)row * 512 + j];
#pragma unroll
  for (int off = 32; off >= 1; off >>= 1) s += __shfl_xor(s, off, 64);
  if (lane == 0) rowsum[mbase + row] = s;
}

// ======== GEMM2: partial[ks][pr][d] = sum_{v in slice} P[pr][v]*Et[d][v] ========
// Ring-3 / BK=32 / minimal-sync (r1 structure, verified): per K-tile 1 barrier +
// 1 counted vmcnt(4) (vmcnt(0) only at last tile); stage t+2 into the slot freed
// at the barrier. 8 waves (2m x 4n), 256x256 tile, setprio, XCD swizzle.
__global__ __launch_bounds__(512, 2) void k_gemm2(
    const bf16_t* __restrict__ P, const bf16_t* __restrict__ Et,
    float* __restrict__ partial, int mtiles, int chunkrows, int kper) {
  __shared__ __align__(16) bf16_t lds[3][16384];   // 96 KB: per buf A 256x32 | B 256x32

  const int tid = threadIdx.x;
  const int lane = tid & 63;
  const int wid = tid >> 6;          // 0..7
  const int wm = wid >> 2;           // 0..1
  const int wn = wid & 3;            // 0..3
  const int c16 = lane & 15, quad = lane >> 4;

  // XCD-chunked swizzle (nwg % 8 == 0 by construction)
  const int nwg = (int)gridDim.x;
  const int xcd = blockIdx.x & 7;
  const int vb = xcd * (nwg >> 3) + ((int)blockIdx.x >> 3);
  const int dtile = vb & 3;
  const int rest = vb >> 2;
  const int mtile = rest % mtiles;
  const int kslice = rest / mtiles;

  const int d0 = dtile * 256;
  const int prow0 = mtile * 256;
  const int kbase = kslice * kper;
  float* __restrict__ o = partial + (size_t)kslice * chunkrows * D_;

  const int l3 = lane >> 3;
  const int cA = (lane & 7) ^ l3;
  const int grA = (l3 << 1) + (cA >> 2);
  const int gcA = (cA & 3) << 3;

  const bf16_t* srcA0 = P  + (size_t)(prow0 + (wid * 2 + 0) * 16 + grA) * V_ + kbase + gcA;
  const bf16_t* srcA1 = P  + (size_t)(prow0 + (wid * 2 + 1) * 16 + grA) * V_ + kbase + gcA;
  const bf16_t* srcB0 = Et + (size_t)(d0   + (wid * 2 + 0) * 16 + grA) * V_ + kbase + gcA;
  const bf16_t* srcB1 = Et + (size_t)(d0   + (wid * 2 + 1) * 16 + grA) * V_ + kbase + gcA;
  const int ldsOfs0 = (wid * 2 + 0) * 16 * 32;
  const int ldsOfs1 = (wid * 2 + 1) * 16 * 32;

  f32x4 acc[8][4];
#pragma unroll
  for (int i = 0; i < 8; i++)
#pragma unroll
    for (int j = 0; j < 4; j++) acc[i][j] = (f32x4){0.f, 0.f, 0.f, 0.f};

#define G2_STAGE(buf, t)                                               \
  do {                                                                 \
    async_copy16(srcA0 + (size_t)(t) * 32, &lds[buf][ldsOfs0]);        \
    async_copy16(srcA1 + (size_t)(t) * 32, &lds[buf][ldsOfs1]);        \
    async_copy16(srcB0 + (size_t)(t) * 32, &lds[buf][8192 + ldsOfs0]); \
    async_copy16(srcB1 + (size_t)(t) * 32, &lds[buf][8192 + ldsOfs1]); \
  } while (0)

  // prologue: stage tiles 0,1 into bufs 0,1
  G2_STAGE(0, 0);
  G2_STAGE(1, 1);
  VMW(0);
  BAR();

  const int NT = kper >> 5;
  int cur = 0;
  for (int t = 0; t < NT; ++t) {
    if (t > 0) {
      if (t < NT - 1) VMW(4);   // drains stage issued 2 tiles ago = this tile's data
      else            VMW(0);
      BAR();
    }
    const int nx2 = (cur == 0) ? 2 : cur - 1;
    if (t < NT - 2) G2_STAGE(nx2, t + 2);

    bf16x8 bfr[4];
#pragma unroll
    for (int j = 0; j < 4; j++) {
      int rn = wn * 64 + j * 16 + c16;
      int pn = rn >> 1;
      int cz = (((rn & 1) << 2) | quad) ^ (pn & 7);
      bfr[j] = *(const bf16x8*)&lds[cur][8192 + pn * 64 + (cz << 3)];
    }
    __builtin_amdgcn_s_setprio(1);
#pragma unroll
    for (int i = 0; i < 8; i++) {
      int rr = wm * 128 + i * 16 + c16;
      int pa = rr >> 1;
      int cz = (((rr & 1) << 2) | quad) ^ (pa & 7);
      bf16x8 a = *(const bf16x8*)&lds[cur][pa * 64 + (cz << 3)];
#pragma unroll
      for (int j = 0; j < 4; j++)
        acc[i][j] = __builtin_amdgcn_mfma_f32_16x16x32_bf16(a, bfr[j], acc[i][j], 0, 0, 0);
    }
    __builtin_amdgcn_s_setprio(0);
    cur = (cur == 2) ? 0 : cur + 1;
  }

  // epilogue: plain fp32 stores into this k-slice's partial
#pragma unroll
  for (int i = 0; i < 8; i++) {
#pragma unroll
    for (int e = 0; e < 4; e++) {
      int pr = prow0 + wm * 128 + i * 16 + quad * 4 + e;
#pragma unroll
      for (int j = 0; j < 4; j++) {
        int d = d0 + wn * 64 + j * 16 + c16;
        o[(size_t)pr * D_ + d] = acc[i][j][e];
      }
    }
  }
#undef G2_STAGE
}

#undef BAR
#undef VMW

// -------- finalize: out[mbase+lr][:] = (sum_z partial[z]) / rowsum --------
__global__ void k_finalize(const float* __restrict__ partial,
                           const float* __restrict__ rowsum, float* __restrict__ out,
                           int mbase, int rows, int ks) {
  int i = blockIdx.x * 256 + threadIdx.x;   // over rows*D/4
  int lr = i >> 8;                          // /(D_/4)
  float inv = 1.0f / rowsum[mbase + lr];
  f32x4 s = (f32x4){0.f, 0.f, 0.f, 0.f};
  for (int z = 0; z < ks; z++) {
    f32x4 a = ((const f32x4*)(partial + (size_t)z * rows * D_))[i];
    s.x += a.x; s.y += a.y; s.z += a.z; s.w += a.w;
  }
  s.x *= inv; s.y *= inv; s.z *= inv; s.w *= inv;
  ((f32x4*)out)[(size_t)mbase * (D_ / 4) + i] = s;
}

// ======== host ========
extern "C" void kernel_launch(void* const* d_in, const int* in_sizes, int n_in,
                              void* d_out, int out_size, void* d_ws, size_t ws_size,
                              hipStream_t stream) {
  const float* xp   = (const float*)d_in[0];   // (B,N,FP,TP)
  const float* E    = (const float*)d_in[1];   // (V,D)
  const float* W    = (const float*)d_in[2];   // (FP,V)
  const float* bias = (const float*)d_in[3];   // (V)
  float* out = (float*)d_out;                  // (M,D)

  char* ws = (char*)d_ws;
  const size_t szXb = (size_t)M_ * FP_ * 2;
  const size_t szWt = (size_t)V_ * FP_ * 2;
  const size_t szEt = (size_t)D_ * V_ * 2;
  const size_t szRs = (size_t)M_ * 4;
  bf16_t* Xb = (bf16_t*)ws;
  bf16_t* Wt = (bf16_t*)(ws + szXb);
  bf16_t* Et = (bf16_t*)(ws + szXb + szWt);
  float* rowsum = (float*)(ws + szXb + szWt + szEt);
  const size_t fixed = szXb + szWt + szEt + szRs;

  const int copt[4] = {8192, 4096, 2048, 1024};
  const int kopt[4] = {2, 4, 10, 20};
  int chunk = 1024, ksv = 20;
  size_t avail = (ws_size > fixed) ? ws_size - fixed : 0;
  for (int i = 0; i < 4; i++) {
    size_t need = (size_t)copt[i] * V_ * 2 + (size_t)kopt[i] * copt[i] * D_ * 4
                + (size_t)copt[i] * 512 * 4;
    if (need <= avail) { chunk = copt[i]; ksv = kopt[i]; break; }
  }
  bf16_t* P = (bf16_t*)(ws + fixed);
  float* partial = (float*)(ws + fixed + (size_t)chunk * V_ * 2);
  float* rs_part = (float*)(ws + fixed + (size_t)chunk * V_ * 2
                            + (size_t)ksv * chunk * D_ * 4);
  const int kper = V_ / ksv;

  k_convert_x<<<B_ * N_, 256, 0, stream>>>(xp, Xb);
  {
    dim3 g(V_ / 64, FP_ / 64);
    k_transpose_cvt<<<g, 256, 0, stream>>>(W, Wt, FP_, V_);
  }
  {
    dim3 g(D_ / 64, V_ / 64);
    k_transpose_cvt<<<g, 256, 0, stream>>>(E, Et, V_, D_);
  }

  for (int mb = 0; mb < M_; mb += chunk) {
    int rows = M_ - mb;
    if (rows > chunk) rows = chunk;

    int nwg1 = VT_ * (rows / 256);
    k_gemm1<<<nwg1, 512, 0, stream>>>(Xb, Wt, bias, P, rs_part, mb);
    k_rowsum_reduce<<<rows / 4, 256, 0, stream>>>(rs_part, rowsum, mb);

    int mt = rows / 256;
    int nwg2 = 4 * mt * ksv;
    k_gemm2<<<nwg2, 512, 0, stream>>>(P, Et, partial, mt, rows, kper);

    k_finalize<<<rows, 256, 0, stream>>>(partial, rowsum, out, mb, rows, ksv);
  }
}

// Round 8
// 1109.034 us; speedup vs baseline: 1.0961x; 1.0355x over previous
//
#include <hip/hip_runtime.h>
#include <cstdint>
#include <cstddef>

typedef __bf16 bf16_t;
typedef __bf16 bf16x8 __attribute__((ext_vector_type(8)));
typedef float f32x4 __attribute__((ext_vector_type(4)));

#define B_  4
#define N_  64
#define FP_ 256
#define TP_ 32
#define V_  32000
#define D_  1024
#define L_  2048
#define M_  8192   // B_*L_
#define VT_ 125    // V_/256

// -------- async global->LDS (16B per lane, wave-uniform LDS base) --------
__device__ __forceinline__ void async_copy16(const void* g, void* l) {
  __builtin_amdgcn_global_load_lds(
      (__attribute__((address_space(1))) void*)g,
      (__attribute__((address_space(3))) void*)l,
      16, 0, 0);
}

// -------- x_prime (B,N,FP,TP) fp32 -> Xb (M,FP) bf16, m = b*L + t*N + n --------
__global__ __launch_bounds__(256) void k_convert_x(const float* __restrict__ xp,
                                                   bf16_t* __restrict__ Xb) {
  __shared__ float tile[256][33];
  const int tid = threadIdx.x;
  const int b = blockIdx.x >> 6;
  const int n = blockIdx.x & 63;
  const float* src = xp + (size_t)(b * N_ + n) * FP_ * TP_;   // (f,t) 256x32
#pragma unroll
  for (int i = 0; i < 32; i++) {
    int idx = i * 256 + tid;
    tile[idx >> 5][idx & 31] = src[idx];
  }
  __syncthreads();
#pragma unroll
  for (int t = 0; t < 32; t++) {
    Xb[(size_t)(b * L_ + t * N_ + n) * FP_ + tid] = (bf16_t)tile[tid][t];
  }
}

// -------- transpose+convert: src (R,C) fp32 -> dst (C,R) bf16 --------
__global__ void k_transpose_cvt(const float* __restrict__ src, bf16_t* __restrict__ dst,
                                int R, int C) {
  __shared__ float tile[64][65];
  int ct = blockIdx.x;
  int rt = blockIdx.y;
  int tid = threadIdx.x;
#pragma unroll
  for (int i = 0; i < 16; i++) {
    int idx = tid + i * 256;
    int a = idx >> 6, bc = idx & 63;
    tile[a][bc] = src[(size_t)(rt * 64 + a) * C + ct * 64 + bc];
  }
  __syncthreads();
#pragma unroll
  for (int i = 0; i < 16; i++) {
    int idx = tid + i * 256;
    int a = idx >> 6, bc = idx & 63;
    dst[(size_t)(ct * 64 + a) * R + rt * 64 + bc] = (bf16_t)tile[bc][a];
  }
}

#define BAR() asm volatile("s_barrier" ::: "memory")
#define VMW(n) asm volatile("s_waitcnt vmcnt(" #n ")" ::: "memory")

// ======== GEMM1: P[pr][v] = exp(X[m]·Wt[v] + bias[v]) ========
// 128x256 tile, ring-3 24KB bufs (72KB -> 2 blocks/CU), minimal-sync:
// per K-tile 1 barrier + counted vmcnt(3) (stage distance 2 tiles).
// 8 waves (2m x 4n), wave tile 64x64, acc[4][4].
__global__ __launch_bounds__(512, 4) void k_gemm1(
    const bf16_t* __restrict__ Xb, const bf16_t* __restrict__ Wt,
    const float* __restrict__ bias, bf16_t* __restrict__ P,
    float* __restrict__ rs_part, int mbase) {
  // ring: buf b at + b*12288 elems; A [0,4096), B [4096,12288).
  // epilogue reuses first 32768 elems (64KB) for the 128x256 bf16 tile.
  __shared__ __align__(16) bf16_t smem[36864];   // 72 KB

  const int tid = threadIdx.x;
  const int lane = tid & 63;
  const int wid = tid >> 6;          // 0..7
  const int wm = wid >> 2;           // 0..1
  const int wn = wid & 3;            // 0..3
  const int c16 = lane & 15, quad = lane >> 4;

  // bijective XCD-chunk swizzle (handles nwg % 8 != 0)
  const int nwg = (int)gridDim.x;
  const int q = nwg >> 3, r = nwg & 7;
  const int xcd = blockIdx.x & 7, bidx = (int)blockIdx.x >> 3;
  const int vb = (xcd < r) ? xcd * (q + 1) + bidx : r + xcd * q + bidx;
  const int vtile = vb % VT_;
  const int mtile = vb / VT_;

  const int v0 = vtile * 256;
  const int prow0 = mtile * 128;
  const int m0 = mbase + prow0;

  // staging lane geometry (verified stage/read involution pair, 16-row windows)
  const int l3 = lane >> 3;
  const int cA = (lane & 7) ^ l3;
  const int grA = (l3 << 1) + (cA >> 2);
  const int gcA = (cA & 3) << 3;

  // A: 128 rows -> 8 windows, wave wid stages window wid.
  // B: 256 rows -> 16 windows, wave wid stages windows wid*2, wid*2+1.
  const bf16_t* srcA  = Xb + (size_t)(m0 + wid * 16 + grA) * FP_ + gcA;
  const bf16_t* srcB0 = Wt + (size_t)(v0 + (wid * 2 + 0) * 16 + grA) * FP_ + gcA;
  const bf16_t* srcB1 = Wt + (size_t)(v0 + (wid * 2 + 1) * 16 + grA) * FP_ + gcA;
  const int ofsA  = wid * 512;             // elems within A region
  const int ofsB0 = (wid * 2 + 0) * 512;   // elems within B region
  const int ofsB1 = (wid * 2 + 1) * 512;

  // bias loads issued before stages; prologue VMW(0) drains all.
  float bv[4];
#pragma unroll
  for (int J = 0; J < 4; J++)
    bv[J] = bias[v0 + wn * 64 + J * 16 + c16];

  f32x4 acc[4][4];
#pragma unroll
  for (int i = 0; i < 4; i++)
#pragma unroll
    for (int j = 0; j < 4; j++) acc[i][j] = (f32x4){0.f, 0.f, 0.f, 0.f};

#define G1_STAGE(buf, t)                                                  \
  do {                                                                    \
    async_copy16(srcA  + (t) * 32, &smem[(buf) * 12288 + ofsA]);          \
    async_copy16(srcB0 + (t) * 32, &smem[(buf) * 12288 + 4096 + ofsB0]);  \
    async_copy16(srcB1 + (t) * 32, &smem[(buf) * 12288 + 4096 + ofsB1]);  \
  } while (0)

  G1_STAGE(0, 0);
  G1_STAGE(1, 1);
  VMW(0);
  BAR();

  const int NT = FP_ >> 5;   // 8
  int cur = 0;
  for (int t = 0; t < NT; ++t) {
    if (t > 0) {
      if (t < NT - 1) VMW(3);   // drains stage(t) (issued 2 tiles ago)
      else            VMW(0);
      BAR();
    }
    const int nx2 = (cur == 0) ? 2 : cur - 1;
    if (t < NT - 2) G1_STAGE(nx2, t + 2);

    const int bo = cur * 12288;
    bf16x8 bfr[4];
#pragma unroll
    for (int j = 0; j < 4; j++) {
      int rn = wn * 64 + j * 16 + c16;
      int pn = rn >> 1;
      int cz = (((rn & 1) << 2) | quad) ^ (pn & 7);
      bfr[j] = *(const bf16x8*)&smem[bo + 4096 + pn * 64 + (cz << 3)];
    }
    __builtin_amdgcn_s_setprio(1);
#pragma unroll
    for (int i = 0; i < 4; i++) {
      int rr = wm * 64 + i * 16 + c16;
      int pa = rr >> 1;
      int cz = (((rr & 1) << 2) | quad) ^ (pa & 7);
      bf16x8 a = *(const bf16x8*)&smem[bo + pa * 64 + (cz << 3)];
#pragma unroll
      for (int j = 0; j < 4; j++)
        acc[i][j] = __builtin_amdgcn_mfma_f32_16x16x32_bf16(a, bfr[j], acc[i][j], 0, 0, 0);
    }
    __builtin_amdgcn_s_setprio(0);
    cur = (cur == 2) ? 0 : cur + 1;
  }

  // epilogue pass 1 (registers only): exp + bf16 round + per-wave 64-col rowsum
#pragma unroll
  for (int I = 0; I < 4; I++) {
    int rowb = wm * 64 + I * 16;
#pragma unroll
    for (int e = 0; e < 4; e++) {
      int row = rowb + quad * 4 + e;
      float s = 0.0f;
#pragma unroll
      for (int J = 0; J < 4; J++) {
        float p = __expf(acc[I][J][e] + bv[J]);
        float pf32 = (float)(bf16_t)p;
        acc[I][J][e] = pf32;
        s += pf32;
      }
#pragma unroll
      for (int off = 1; off < 16; off <<= 1) s += __shfl_xor(s, off, 16);
      if (c16 == 0)
        rs_part[(size_t)(prow0 + row) * 512 + vtile * 4 + wn] = s;
    }
  }

  // epilogue pass 2: stage 128x256 bf16 tile in LDS (row&7 XOR chunk swizzle)
  __syncthreads();
#pragma unroll
  for (int I = 0; I < 4; I++) {
    int rowb = wm * 64 + I * 16;
#pragma unroll
    for (int e = 0; e < 4; e++) {
      int row = rowb + quad * 4 + e;
#pragma unroll
      for (int J = 0; J < 4; J++) {
        int ch = wn * 8 + J * 2 + (c16 >> 3);
        smem[row * 256 + ((ch ^ (row & 7)) << 3) + (c16 & 7)] = (bf16_t)acc[I][J][e];
      }
    }
  }
  __syncthreads();
  // coalesced b128 stores: 128 rows x 32 chunks = 4096 lane-stores, 8/thread
#pragma unroll
  for (int it = 0; it < 8; it++) {
    int idx2 = it * 512 + tid;
    int row = idx2 >> 5, ch = idx2 & 31;
    *(bf16x8*)&P[(size_t)(prow0 + row) * V_ + v0 + ch * 8] =
        *(const bf16x8*)&smem[row * 256 + ((ch ^ (row & 7)) << 3)];
  }
#undef G1_STAGE
}

// -------- rowsum reduce: rowsum[mbase+row] = sum of 500 per-wave partials --------
__global__ void k_rowsum_reduce(const float* __restrict__ rs_part,
                                float* __restrict__ rowsum, int mbase) {
  int row = blockIdx.x * 4 + (threadIdx.x >> 6);
  int lane = threadIdx.x & 63;
  float s = 0.0f;
  for (int j = lane; j < VT_ * 4; j += 64) s += rs_part[(size_t)row * 512 + j];
#pragma unroll
  for (int off = 32; off >= 1; off >>= 1) s += __shfl_xor(s, off, 64);
  if (lane == 0) rowsum[mbase + row] = s;
}

// ======== GEMM2: partial[ks][pr][d] = sum_{v in slice} P[pr][v]*Et[d][v] ========
// 128x256 tile, ring-3 24KB bufs (72KB -> 2 blocks/CU), minimal-sync
// (1 barrier + counted vmcnt(3)/tile, stage distance 2), 8 waves (2m x 4n),
// setprio, XCD swizzle. Grid sized to 512 blocks = 2/CU.
__global__ __launch_bounds__(512, 4) void k_gemm2(
    const bf16_t* __restrict__ P, const bf16_t* __restrict__ Et,
    float* __restrict__ partial, int mtiles, int chunkrows, int kper) {
  __shared__ __align__(16) bf16_t lds[3][12288];   // 72 KB: per buf A 128x32 | B 256x32

  const int tid = threadIdx.x;
  const int lane = tid & 63;
  const int wid = tid >> 6;          // 0..7
  const int wm = wid >> 2;           // 0..1
  const int wn = wid & 3;            // 0..3
  const int c16 = lane & 15, quad = lane >> 4;

  // XCD-chunked swizzle (nwg % 8 == 0 by construction)
  const int nwg = (int)gridDim.x;
  const int xcd = blockIdx.x & 7;
  const int vb = xcd * (nwg >> 3) + ((int)blockIdx.x >> 3);
  const int dtile = vb & 3;
  const int rest = vb >> 2;
  const int mtile = rest % mtiles;
  const int kslice = rest / mtiles;

  const int d0 = dtile * 256;
  const int prow0 = mtile * 128;
  const int kbase = kslice * kper;
  float* __restrict__ o = partial + (size_t)kslice * chunkrows * D_;

  const int l3 = lane >> 3;
  const int cA = (lane & 7) ^ l3;
  const int grA = (l3 << 1) + (cA >> 2);
  const int gcA = (cA & 3) << 3;

  const bf16_t* srcA  = P  + (size_t)(prow0 + wid * 16 + grA) * V_ + kbase + gcA;
  const bf16_t* srcB0 = Et + (size_t)(d0 + (wid * 2 + 0) * 16 + grA) * V_ + kbase + gcA;
  const bf16_t* srcB1 = Et + (size_t)(d0 + (wid * 2 + 1) * 16 + grA) * V_ + kbase + gcA;
  const int ofsA  = wid * 512;
  const int ofsB0 = (wid * 2 + 0) * 512;
  const int ofsB1 = (wid * 2 + 1) * 512;

  f32x4 acc[4][4];
#pragma unroll
  for (int i = 0; i < 4; i++)
#pragma unroll
    for (int j = 0; j < 4; j++) acc[i][j] = (f32x4){0.f, 0.f, 0.f, 0.f};

#define G2_STAGE(buf, t)                                                \
  do {                                                                  \
    async_copy16(srcA  + (size_t)(t) * 32, &lds[buf][ofsA]);            \
    async_copy16(srcB0 + (size_t)(t) * 32, &lds[buf][4096 + ofsB0]);    \
    async_copy16(srcB1 + (size_t)(t) * 32, &lds[buf][4096 + ofsB1]);    \
  } while (0)

  G2_STAGE(0, 0);
  G2_STAGE(1, 1);
  VMW(0);
  BAR();

  const int NT = kper >> 5;
  int cur = 0;
  for (int t = 0; t < NT; ++t) {
    if (t > 0) {
      if (t < NT - 1) VMW(3);   // drains stage(t) (issued 2 tiles ago)
      else            VMW(0);
      BAR();
    }
    const int nx2 = (cur == 0) ? 2 : cur - 1;
    if (t < NT - 2) G2_STAGE(nx2, t + 2);

    bf16x8 bfr[4];
#pragma unroll
    for (int j = 0; j < 4; j++) {
      int rn = wn * 64 + j * 16 + c16;
      int pn = rn >> 1;
      int cz = (((rn & 1) << 2) | quad) ^ (pn & 7);
      bfr[j] = *(const bf16x8*)&lds[cur][4096 + pn * 64 + (cz << 3)];
    }
    __builtin_amdgcn_s_setprio(1);
#pragma unroll
    for (int i = 0; i < 4; i++) {
      int rr = wm * 64 + i * 16 + c16;
      int pa = rr >> 1;
      int cz = (((rr & 1) << 2) | quad) ^ (pa & 7);
      bf16x8 a = *(const bf16x8*)&lds[cur][pa * 64 + (cz << 3)];
#pragma unroll
      for (int j = 0; j < 4; j++)
        acc[i][j] = __builtin_amdgcn_mfma_f32_16x16x32_bf16(a, bfr[j], acc[i][j], 0, 0, 0);
    }
    __builtin_amdgcn_s_setprio(0);
    cur = (cur == 2) ? 0 : cur + 1;
  }

  // epilogue: plain fp32 stores into this k-slice's partial
#pragma unroll
  for (int i = 0; i < 4; i++) {
#pragma unroll
    for (int e = 0; e < 4; e++) {
      int pr = prow0 + wm * 64 + i * 16 + quad * 4 + e;
#pragma unroll
      for (int j = 0; j < 4; j++) {
        int d = d0 + wn * 64 + j * 16 + c16;
        o[(size_t)pr * D_ + d] = acc[i][j][e];
      }
    }
  }
#undef G2_STAGE
}

#undef BAR
#undef VMW

// -------- finalize: out[mbase+lr][:] = (sum_z partial[z]) / rowsum --------
__global__ void k_finalize(const float* __restrict__ partial,
                           const float* __restrict__ rowsum, float* __restrict__ out,
                           int mbase, int rows, int ks) {
  int i = blockIdx.x * 256 + threadIdx.x;   // over rows*D/4
  int lr = i >> 8;                          // /(D_/4)
  float inv = 1.0f / rowsum[mbase + lr];
  f32x4 s = (f32x4){0.f, 0.f, 0.f, 0.f};
  for (int z = 0; z < ks; z++) {
    f32x4 a = ((const f32x4*)(partial + (size_t)z * rows * D_))[i];
    s.x += a.x; s.y += a.y; s.z += a.z; s.w += a.w;
  }
  s.x *= inv; s.y *= inv; s.z *= inv; s.w *= inv;
  ((f32x4*)out)[(size_t)mbase * (D_ / 4) + i] = s;
}

// ======== host ========
extern "C" void kernel_launch(void* const* d_in, const int* in_sizes, int n_in,
                              void* d_out, int out_size, void* d_ws, size_t ws_size,
                              hipStream_t stream) {
  const float* xp   = (const float*)d_in[0];   // (B,N,FP,TP)
  const float* E    = (const float*)d_in[1];   // (V,D)
  const float* W    = (const float*)d_in[2];   // (FP,V)
  const float* bias = (const float*)d_in[3];   // (V)
  float* out = (float*)d_out;                  // (M,D)

  char* ws = (char*)d_ws;
  const size_t szXb = (size_t)M_ * FP_ * 2;
  const size_t szWt = (size_t)V_ * FP_ * 2;
  const size_t szEt = (size_t)D_ * V_ * 2;
  const size_t szRs = (size_t)M_ * 4;
  bf16_t* Xb = (bf16_t*)ws;
  bf16_t* Wt = (bf16_t*)(ws + szXb);
  bf16_t* Et = (bf16_t*)(ws + szXb + szWt);
  float* rowsum = (float*)(ws + szXb + szWt + szEt);
  const size_t fixed = szXb + szWt + szEt + szRs;

  // ks chosen so nwg2 = 4 * (chunk/128) * ks = 512 (2 blocks/CU) and
  // kper = V/ks divisible by 32: {8192:2, 4096:4, 2048:8, 1024:16}.
  const int copt[4] = {8192, 4096, 2048, 1024};
  const int kopt[4] = {2, 4, 8, 16};
  int chunk = 1024, ksv = 16;
  size_t avail = (ws_size > fixed) ? ws_size - fixed : 0;
  for (int i = 0; i < 4; i++) {
    size_t need = (size_t)copt[i] * V_ * 2 + (size_t)kopt[i] * copt[i] * D_ * 4
                + (size_t)copt[i] * 512 * 4;
    if (need <= avail) { chunk = copt[i]; ksv = kopt[i]; break; }
  }
  bf16_t* P = (bf16_t*)(ws + fixed);
  float* partial = (float*)(ws + fixed + (size_t)chunk * V_ * 2);
  float* rs_part = (float*)(ws + fixed + (size_t)chunk * V_ * 2
                            + (size_t)ksv * chunk * D_ * 4);
  const int kper = V_ / ksv;

  k_convert_x<<<B_ * N_, 256, 0, stream>>>(xp, Xb);
  {
    dim3 g(V_ / 64, FP_ / 64);
    k_transpose_cvt<<<g, 256, 0, stream>>>(W, Wt, FP_, V_);
  }
  {
    dim3 g(D_ / 64, V_ / 64);
    k_transpose_cvt<<<g, 256, 0, stream>>>(E, Et, V_, D_);
  }

  for (int mb = 0; mb < M_; mb += chunk) {
    int rows = M_ - mb;
    if (rows > chunk) rows = chunk;

    int nwg1 = VT_ * (rows / 128);
    k_gemm1<<<nwg1, 512, 0, stream>>>(Xb, Wt, bias, P, rs_part, mb);
    k_rowsum_reduce<<<rows / 4, 256, 0, stream>>>(rs_part, rowsum, mb);

    int mt = rows / 128;
    int nwg2 = 4 * mt * ksv;
    k_gemm2<<<nwg2, 512, 0, stream>>>(P, Et, partial, mt, rows, kper);

    k_finalize<<<rows, 256, 0, stream>>>(partial, rowsum, out, mb, rows, ksv);
  }
}

// Round 9
// 1064.247 us; speedup vs baseline: 1.1422x; 1.0421x over previous
//
#include <hip/hip_runtime.h>
#include <cstdint>
#include <cstddef>

typedef __bf16 bf16_t;
typedef __bf16 bf16x8 __attribute__((ext_vector_type(8)));
typedef float f32x4 __attribute__((ext_vector_type(4)));

#define B_  4
#define N_  64
#define FP_ 256
#define TP_ 32
#define V_  32000
#define D_  1024
#define L_  2048
#define M_  8192   // B_*L_
#define VT_ 125    // V_/256

// -------- async global->LDS (16B per lane, wave-uniform LDS base) --------
__device__ __forceinline__ void async_copy16(const void* g, void* l) {
  __builtin_amdgcn_global_load_lds(
      (__attribute__((address_space(1))) void*)g,
      (__attribute__((address_space(3))) void*)l,
      16, 0, 0);
}

// -------- x_prime (B,N,FP,TP) fp32 -> Xb (M,FP) bf16, m = b*L + t*N + n --------
__global__ __launch_bounds__(256) void k_convert_x(const float* __restrict__ xp,
                                                   bf16_t* __restrict__ Xb) {
  __shared__ float tile[256][33];
  const int tid = threadIdx.x;
  const int b = blockIdx.x >> 6;
  const int n = blockIdx.x & 63;
  const float* src = xp + (size_t)(b * N_ + n) * FP_ * TP_;   // (f,t) 256x32
#pragma unroll
  for (int i = 0; i < 32; i++) {
    int idx = i * 256 + tid;
    tile[idx >> 5][idx & 31] = src[idx];
  }
  __syncthreads();
#pragma unroll
  for (int t = 0; t < 32; t++) {
    Xb[(size_t)(b * L_ + t * N_ + n) * FP_ + tid] = (bf16_t)tile[tid][t];
  }
}

// -------- transpose+convert: src (R,C) fp32 -> dst (C,R) bf16 --------
__global__ void k_transpose_cvt(const float* __restrict__ src, bf16_t* __restrict__ dst,
                                int R, int C) {
  __shared__ float tile[64][65];
  int ct = blockIdx.x;
  int rt = blockIdx.y;
  int tid = threadIdx.x;
#pragma unroll
  for (int i = 0; i < 16; i++) {
    int idx = tid + i * 256;
    int a = idx >> 6, bc = idx & 63;
    tile[a][bc] = src[(size_t)(rt * 64 + a) * C + ct * 64 + bc];
  }
  __syncthreads();
#pragma unroll
  for (int i = 0; i < 16; i++) {
    int idx = tid + i * 256;
    int a = idx >> 6, bc = idx & 63;
    dst[(size_t)(ct * 64 + a) * R + rt * 64 + bc] = (bf16_t)tile[bc][a];
  }
}

#define BAR() asm volatile("s_barrier" ::: "memory")
#define VMW(n) asm volatile("s_waitcnt vmcnt(" #n ")" ::: "memory")

// ======== GEMM1: P[pr][v] = exp(X[m]·Wt[v] + bias[v]) ======== (r8 version, kept)
// 128x256 tile, ring-3 24KB bufs (72KB -> 2 blocks/CU), minimal-sync:
// per K-tile 1 barrier + counted vmcnt(3) (stage distance 2 tiles).
__global__ __launch_bounds__(512, 4) void k_gemm1(
    const bf16_t* __restrict__ Xb, const bf16_t* __restrict__ Wt,
    const float* __restrict__ bias, bf16_t* __restrict__ P,
    float* __restrict__ rs_part, int mbase) {
  __shared__ __align__(16) bf16_t smem[36864];   // 72 KB

  const int tid = threadIdx.x;
  const int lane = tid & 63;
  const int wid = tid >> 6;          // 0..7
  const int wm = wid >> 2;           // 0..1
  const int wn = wid & 3;            // 0..3
  const int c16 = lane & 15, quad = lane >> 4;

  const int nwg = (int)gridDim.x;
  const int q = nwg >> 3, r = nwg & 7;
  const int xcd = blockIdx.x & 7, bidx = (int)blockIdx.x >> 3;
  const int vb = (xcd < r) ? xcd * (q + 1) + bidx : r + xcd * q + bidx;
  const int vtile = vb % VT_;
  const int mtile = vb / VT_;

  const int v0 = vtile * 256;
  const int prow0 = mtile * 128;
  const int m0 = mbase + prow0;

  const int l3 = lane >> 3;
  const int cA = (lane & 7) ^ l3;
  const int grA = (l3 << 1) + (cA >> 2);
  const int gcA = (cA & 3) << 3;

  const bf16_t* srcA  = Xb + (size_t)(m0 + wid * 16 + grA) * FP_ + gcA;
  const bf16_t* srcB0 = Wt + (size_t)(v0 + (wid * 2 + 0) * 16 + grA) * FP_ + gcA;
  const bf16_t* srcB1 = Wt + (size_t)(v0 + (wid * 2 + 1) * 16 + grA) * FP_ + gcA;
  const int ofsA  = wid * 512;
  const int ofsB0 = (wid * 2 + 0) * 512;
  const int ofsB1 = (wid * 2 + 1) * 512;

  float bv[4];
#pragma unroll
  for (int J = 0; J < 4; J++)
    bv[J] = bias[v0 + wn * 64 + J * 16 + c16];

  f32x4 acc[4][4];
#pragma unroll
  for (int i = 0; i < 4; i++)
#pragma unroll
    for (int j = 0; j < 4; j++) acc[i][j] = (f32x4){0.f, 0.f, 0.f, 0.f};

#define G1_STAGE(buf, t)                                                  \
  do {                                                                    \
    async_copy16(srcA  + (t) * 32, &smem[(buf) * 12288 + ofsA]);          \
    async_copy16(srcB0 + (t) * 32, &smem[(buf) * 12288 + 4096 + ofsB0]);  \
    async_copy16(srcB1 + (t) * 32, &smem[(buf) * 12288 + 4096 + ofsB1]);  \
  } while (0)

  G1_STAGE(0, 0);
  G1_STAGE(1, 1);
  VMW(0);
  BAR();

  const int NT = FP_ >> 5;   // 8
  int cur = 0;
  for (int t = 0; t < NT; ++t) {
    if (t > 0) {
      if (t < NT - 1) VMW(3);
      else            VMW(0);
      BAR();
    }
    const int nx2 = (cur == 0) ? 2 : cur - 1;
    if (t < NT - 2) G1_STAGE(nx2, t + 2);

    const int bo = cur * 12288;
    bf16x8 bfr[4];
#pragma unroll
    for (int j = 0; j < 4; j++) {
      int rn = wn * 64 + j * 16 + c16;
      int pn = rn >> 1;
      int cz = (((rn & 1) << 2) | quad) ^ (pn & 7);
      bfr[j] = *(const bf16x8*)&smem[bo + 4096 + pn * 64 + (cz << 3)];
    }
    __builtin_amdgcn_s_setprio(1);
#pragma unroll
    for (int i = 0; i < 4; i++) {
      int rr = wm * 64 + i * 16 + c16;
      int pa = rr >> 1;
      int cz = (((rr & 1) << 2) | quad) ^ (pa & 7);
      bf16x8 a = *(const bf16x8*)&smem[bo + pa * 64 + (cz << 3)];
#pragma unroll
      for (int j = 0; j < 4; j++)
        acc[i][j] = __builtin_amdgcn_mfma_f32_16x16x32_bf16(a, bfr[j], acc[i][j], 0, 0, 0);
    }
    __builtin_amdgcn_s_setprio(0);
    cur = (cur == 2) ? 0 : cur + 1;
  }

  // epilogue pass 1: exp + bf16 round + per-wave 64-col partial rowsum
#pragma unroll
  for (int I = 0; I < 4; I++) {
    int rowb = wm * 64 + I * 16;
#pragma unroll
    for (int e = 0; e < 4; e++) {
      int row = rowb + quad * 4 + e;
      float s = 0.0f;
#pragma unroll
      for (int J = 0; J < 4; J++) {
        float p = __expf(acc[I][J][e] + bv[J]);
        float pf32 = (float)(bf16_t)p;
        acc[I][J][e] = pf32;
        s += pf32;
      }
#pragma unroll
      for (int off = 1; off < 16; off <<= 1) s += __shfl_xor(s, off, 16);
      if (c16 == 0)
        rs_part[(size_t)(prow0 + row) * 512 + vtile * 4 + wn] = s;
    }
  }

  // epilogue pass 2: stage 128x256 bf16 tile in LDS, coalesced b128 stores
  __syncthreads();
#pragma unroll
  for (int I = 0; I < 4; I++) {
    int rowb = wm * 64 + I * 16;
#pragma unroll
    for (int e = 0; e < 4; e++) {
      int row = rowb + quad * 4 + e;
#pragma unroll
      for (int J = 0; J < 4; J++) {
        int ch = wn * 8 + J * 2 + (c16 >> 3);
        smem[row * 256 + ((ch ^ (row & 7)) << 3) + (c16 & 7)] = (bf16_t)acc[I][J][e];
      }
    }
  }
  __syncthreads();
#pragma unroll
  for (int it = 0; it < 8; it++) {
    int idx2 = it * 512 + tid;
    int row = idx2 >> 5, ch = idx2 & 31;
    *(bf16x8*)&P[(size_t)(prow0 + row) * V_ + v0 + ch * 8] =
        *(const bf16x8*)&smem[row * 256 + ((ch ^ (row & 7)) << 3)];
  }
#undef G1_STAGE
}

// -------- rowsum reduce --------
__global__ void k_rowsum_reduce(const float* __restrict__ rs_part,
                                float* __restrict__ rowsum, int mbase) {
  int row = blockIdx.x * 4 + (threadIdx.x >> 6);
  int lane = threadIdx.x & 63;
  float s = 0.0f;
  for (int j = lane; j < VT_ * 4; j += 64) s += rs_part[(size_t)row * 512 + j];
#pragma unroll
  for (int off = 32; off >= 1; off >>= 1) s += __shfl_xor(s, off, 64);
  if (lane == 0) rowsum[mbase + row] = s;
}

// ======== GEMM2: partial[ks][pr][d] = sum_{v in slice} P[pr][v]*Et[d][v] ========
// 256x256 tile, BK=64, ring-2 (128 KB), ONE vmcnt(0)+barrier per K-tile
// (issue->wait distance = full tile >> HBM latency, so the drain is free).
// kk-subtiled LDS [buf][kk][8192] reusing the verified stage/read involution
// per K32-half. 8 waves (2m x 4n), setprio, XCD swizzle.
__global__ __launch_bounds__(512, 2) void k_gemm2(
    const bf16_t* __restrict__ P, const bf16_t* __restrict__ Et,
    float* __restrict__ partial, int mtiles, int chunkrows, int kper) {
  __shared__ __align__(16) bf16_t lds[2][32768];  // per buf: A[kk][8192] | B[kk][8192]

  const int tid = threadIdx.x;
  const int lane = tid & 63;
  const int wid = tid >> 6;          // 0..7
  const int wm = wid >> 2;           // 0..1
  const int wn = wid & 3;            // 0..3
  const int c16 = lane & 15, quad = lane >> 4;

  // XCD-chunked swizzle (nwg % 8 == 0 by construction)
  const int nwg = (int)gridDim.x;
  const int xcd = blockIdx.x & 7;
  const int vb = xcd * (nwg >> 3) + ((int)blockIdx.x >> 3);
  const int dtile = vb & 3;
  const int rest = vb >> 2;
  const int mtile = rest % mtiles;
  const int kslice = rest / mtiles;

  const int d0 = dtile * 256;
  const int prow0 = mtile * 256;
  const int kbase = kslice * kper;
  float* __restrict__ o = partial + (size_t)kslice * chunkrows * D_;

  const int l3 = lane >> 3;
  const int cA = (lane & 7) ^ l3;
  const int grA = (l3 << 1) + (cA >> 2);
  const int gcA = (cA & 3) << 3;

  const bf16_t* srcA0 = P  + (size_t)(prow0 + (wid * 2 + 0) * 16 + grA) * V_ + kbase + gcA;
  const bf16_t* srcA1 = P  + (size_t)(prow0 + (wid * 2 + 1) * 16 + grA) * V_ + kbase + gcA;
  const bf16_t* srcB0 = Et + (size_t)(d0   + (wid * 2 + 0) * 16 + grA) * V_ + kbase + gcA;
  const bf16_t* srcB1 = Et + (size_t)(d0   + (wid * 2 + 1) * 16 + grA) * V_ + kbase + gcA;
  const int ofs0 = (wid * 2 + 0) * 512;
  const int ofs1 = (wid * 2 + 1) * 512;

  f32x4 acc[8][4];
#pragma unroll
  for (int i = 0; i < 8; i++)
#pragma unroll
    for (int j = 0; j < 4; j++) acc[i][j] = (f32x4){0.f, 0.f, 0.f, 0.f};

  // 8 loads/thread/tile: A,B x 2 windows x 2 kk-halves
#define G2_STAGE(buf, t)                                                \
  do {                                                                  \
    const bf16_t* a0_ = srcA0 + (size_t)(t) * 64;                       \
    const bf16_t* a1_ = srcA1 + (size_t)(t) * 64;                       \
    const bf16_t* b0_ = srcB0 + (size_t)(t) * 64;                       \
    const bf16_t* b1_ = srcB1 + (size_t)(t) * 64;                       \
    async_copy16(a0_,      &lds[buf][ofs0]);                            \
    async_copy16(a0_ + 32, &lds[buf][8192 + ofs0]);                     \
    async_copy16(a1_,      &lds[buf][ofs1]);                            \
    async_copy16(a1_ + 32, &lds[buf][8192 + ofs1]);                     \
    async_copy16(b0_,      &lds[buf][16384 + ofs0]);                    \
    async_copy16(b0_ + 32, &lds[buf][24576 + ofs0]);                    \
    async_copy16(b1_,      &lds[buf][16384 + ofs1]);                    \
    async_copy16(b1_ + 32, &lds[buf][24576 + ofs1]);                    \
  } while (0)

  // prologue: stage tile 0, full drain once
  G2_STAGE(0, 0);
  VMW(0);
  BAR();

  const int NT = kper >> 6;
  for (int t = 0; t < NT; ++t) {
    const int cur = t & 1, nb = cur ^ 1;
    const bool pf = (t + 1 < NT);
    // issue next tile's stage first: DMA proceeds under this tile's compute;
    // buf nb was fully consumed before the barrier that ended iter t-1.
    if (pf) G2_STAGE(nb, t + 1);

#pragma unroll
    for (int kk = 0; kk < 2; kk++) {
      const int ko = kk * 8192;
      bf16x8 bfr[4];
#pragma unroll
      for (int j = 0; j < 4; j++) {
        int rn = wn * 64 + j * 16 + c16;
        int pn = rn >> 1;
        int cz = (((rn & 1) << 2) | quad) ^ (pn & 7);
        bfr[j] = *(const bf16x8*)&lds[cur][16384 + ko + pn * 64 + (cz << 3)];
      }
      __builtin_amdgcn_s_setprio(1);
#pragma unroll
      for (int i = 0; i < 8; i++) {
        int rr = wm * 128 + i * 16 + c16;
        int pa = rr >> 1;
        int cz = (((rr & 1) << 2) | quad) ^ (pa & 7);
        bf16x8 a = *(const bf16x8*)&lds[cur][ko + pa * 64 + (cz << 3)];
#pragma unroll
        for (int j = 0; j < 4; j++)
          acc[i][j] = __builtin_amdgcn_mfma_f32_16x16x32_bf16(a, bfr[j], acc[i][j], 0, 0, 0);
      }
      __builtin_amdgcn_s_setprio(0);
    }

    if (pf) {
      VMW(0);   // stage(t+1) issued a full tile ago -> already landed; near-free
      BAR();    // all waves done reading cur; nb ready for all
    }
  }

  // epilogue: plain fp32 stores into this k-slice's partial
#pragma unroll
  for (int i = 0; i < 8; i++) {
#pragma unroll
    for (int e = 0; e < 4; e++) {
      int pr = prow0 + wm * 128 + i * 16 + quad * 4 + e;
#pragma unroll
      for (int j = 0; j < 4; j++) {
        int d = d0 + wn * 64 + j * 16 + c16;
        o[(size_t)pr * D_ + d] = acc[i][j][e];
      }
    }
  }
#undef G2_STAGE
}

#undef BAR
#undef VMW

// -------- finalize: out[mbase+lr][:] = (sum_z partial[z]) / rowsum --------
__global__ void k_finalize(const float* __restrict__ partial,
                           const float* __restrict__ rowsum, float* __restrict__ out,
                           int mbase, int rows, int ks) {
  int i = blockIdx.x * 256 + threadIdx.x;   // over rows*D/4
  int lr = i >> 8;                          // /(D_/4)
  float inv = 1.0f / rowsum[mbase + lr];
  f32x4 s = (f32x4){0.f, 0.f, 0.f, 0.f};
  for (int z = 0; z < ks; z++) {
    f32x4 a = ((const f32x4*)(partial + (size_t)z * rows * D_))[i];
    s.x += a.x; s.y += a.y; s.z += a.z; s.w += a.w;
  }
  s.x *= inv; s.y *= inv; s.z *= inv; s.w *= inv;
  ((f32x4*)out)[(size_t)mbase * (D_ / 4) + i] = s;
}

// ======== host ========
extern "C" void kernel_launch(void* const* d_in, const int* in_sizes, int n_in,
                              void* d_out, int out_size, void* d_ws, size_t ws_size,
                              hipStream_t stream) {
  const float* xp   = (const float*)d_in[0];   // (B,N,FP,TP)
  const float* E    = (const float*)d_in[1];   // (V,D)
  const float* W    = (const float*)d_in[2];   // (FP,V)
  const float* bias = (const float*)d_in[3];   // (V)
  float* out = (float*)d_out;                  // (M,D)

  char* ws = (char*)d_ws;
  const size_t szXb = (size_t)M_ * FP_ * 2;
  const size_t szWt = (size_t)V_ * FP_ * 2;
  const size_t szEt = (size_t)D_ * V_ * 2;
  const size_t szRs = (size_t)M_ * 4;
  bf16_t* Xb = (bf16_t*)ws;
  bf16_t* Wt = (bf16_t*)(ws + szXb);
  bf16_t* Et = (bf16_t*)(ws + szXb + szWt);
  float* rowsum = (float*)(ws + szXb + szWt + szEt);
  const size_t fixed = szXb + szWt + szEt + szRs;

  // ks | 500 so kper = V/ks is divisible by 64; nwg2 = 4*(chunk/256)*ks:
  // {8192:2 -> 256, 4096:4 -> 256, 2048:10 -> 320, 1024:20 -> 320}
  const int copt[4] = {8192, 4096, 2048, 1024};
  const int kopt[4] = {2, 4, 10, 20};
  int chunk = 1024, ksv = 20;
  size_t avail = (ws_size > fixed) ? ws_size - fixed : 0;
  for (int i = 0; i < 4; i++) {
    size_t need = (size_t)copt[i] * V_ * 2 + (size_t)kopt[i] * copt[i] * D_ * 4
                + (size_t)copt[i] * 512 * 4;
    if (need <= avail) { chunk = copt[i]; ksv = kopt[i]; break; }
  }
  bf16_t* P = (bf16_t*)(ws + fixed);
  float* partial = (float*)(ws + fixed + (size_t)chunk * V_ * 2);
  float* rs_part = (float*)(ws + fixed + (size_t)chunk * V_ * 2
                            + (size_t)ksv * chunk * D_ * 4);
  const int kper = V_ / ksv;

  k_convert_x<<<B_ * N_, 256, 0, stream>>>(xp, Xb);
  {
    dim3 g(V_ / 64, FP_ / 64);
    k_transpose_cvt<<<g, 256, 0, stream>>>(W, Wt, FP_, V_);
  }
  {
    dim3 g(D_ / 64, V_ / 64);
    k_transpose_cvt<<<g, 256, 0, stream>>>(E, Et, V_, D_);
  }

  for (int mb = 0; mb < M_; mb += chunk) {
    int rows = M_ - mb;
    if (rows > chunk) rows = chunk;

    int nwg1 = VT_ * (rows / 128);
    k_gemm1<<<nwg1, 512, 0, stream>>>(Xb, Wt, bias, P, rs_part, mb);
    k_rowsum_reduce<<<rows / 4, 256, 0, stream>>>(rs_part, rowsum, mb);

    int mt2 = rows / 256;
    int nwg2 = 4 * mt2 * ksv;
    k_gemm2<<<nwg2, 512, 0, stream>>>(P, Et, partial, mt2, rows, kper);

    k_finalize<<<rows, 256, 0, stream>>>(partial, rowsum, out, mb, rows, ksv);
  }
}